// Round 18
// baseline (157.585 us; speedup 1.0000x reference)
//
#include <hip/hip_runtime.h>

#define NUM_NETS     100000
#define PINS_PER_NET 5
#define NUM_PINS     (NUM_NETS * PINS_PER_NET)
#define NB           512
#define BIN_H        1.953125f          /* 1000/512, exact in fp32 */
#define INV_H        0.512f             /* 512/1000 */
#define OUT_SCALE    (1.0f / 195.3125f) /* 1/(BIN_SIZE_X * 100 tracks) */

#define SW           8                  /* stripe width (x bins) */
#define NSTRIPES     (NB / SW)          /* 64 */
#define CAP          24576              /* items per stripe bucket (worst ~16K) */
#define GBLK         256                /* fused kernel blocks (1/CU, co-resident) */

#define FXS          2097152.0f         /* 2^21 fixed-point scale */
#define INV_FXS      (1.0f / 2097152.0f)

// ---------------------------------------------------------------------------
// K_0: zero cursors[64] + flags[64] + done[1] each replay (poison-safe init).
// ---------------------------------------------------------------------------
__global__ void zero_kernel(int* __restrict__ p) {
    if (threadIdx.x < 160) p[threadIdx.x] = 0;
}

// ---------------------------------------------------------------------------
// K_F: fused emit + barrier + stripe + lookback + epilogue.
// Phase E: all 256 blocks; 1 net/thread; LDS-aggregated cursor reservation;
//          items written as device-scope relaxed atomic u64 pairs (visible
//          across XCDs without a kernel-boundary L2 flush).
// Barrier: done-counter (atomicAdd + thread-0 spin; all blocks co-resident).
// Phase S: blocks 0..63 = R17 stripe_finish body (atomic u64 item loads).
// ---------------------------------------------------------------------------
__global__ __launch_bounds__(1024) void fused_kernel(
        const float* __restrict__ pin_pos,
        const int*   __restrict__ flat_netpin,
        const float* __restrict__ net_weights,
        int* __restrict__ gcur,
        unsigned long long* __restrict__ bkt64,
        float* __restrict__ Th,  float* __restrict__ Tv,
        int* __restrict__ flag, int* __restrict__ done,
        float* __restrict__ out) {
    __shared__ int   lcnt[NSTRIPES];
    __shared__ int   lbase[NSTRIPES];
    __shared__ int   acc[2 * SW * NB];          /* 32 KB: H then V */
    __shared__ float wsc[32];
    __shared__ float offHs[2][NB];              /* 2 KB */
    __shared__ float offVs[2][NB];              /* 2 KB */
    int tid = threadIdx.x;
    int bid = blockIdx.x;

    /* ================= Phase E: bbox + emit ================= */
    if (tid < NSTRIPES) lcnt[tid] = 0;
    __syncthreads();

    int n = bid * 1024 + tid;
    bool valid = n < NUM_NETS;
    float xmn = 1e30f, xmx = -1e30f, ymn = 1e30f, ymx = -1e30f;
    float wh = 0.f, wv = 0.f;
    int kx1 = 0, kx2 = 0;
    if (valid) {
#pragma unroll
        for (int p = 0; p < PINS_PER_NET; ++p) {
            int pi  = flat_netpin[n * PINS_PER_NET + p];
            float x = pin_pos[pi];
            float y = pin_pos[NUM_PINS + pi];
            xmn = fminf(xmn, x); xmx = fmaxf(xmx, x);
            ymn = fminf(ymn, y); ymx = fmaxf(ymx, y);
        }
        float w = net_weights[n];
        wh = w / (ymx - ymn);
        wv = w / (xmx - xmn);
        kx1 = min(NB - 1, (int)(xmn * INV_H));
        kx2 = min(NB - 1, (int)(xmx * INV_H));
#pragma unroll
        for (int cx = 0; cx < 2; ++cx) {
            int kx = cx ? kx2 : kx1;
            int s0 = kx >> 3;
            atomicAdd(&lcnt[s0], 2);
            if (kx + 1 < NB && ((kx + 1) >> 3) != s0)
                atomicAdd(&lcnt[(kx + 1) >> 3], 2);
        }
    }
    __syncthreads();
    if (tid < NSTRIPES) {
        int c = lcnt[tid];
        lbase[tid] = c ? atomicAdd(&gcur[tid], c) : 0;  /* device scope */
        lcnt[tid] = 0;
    }
    __syncthreads();
    if (valid) {
#pragma unroll
        for (int cx = 0; cx < 2; ++cx) {
            int   kx = cx ? kx2 : kx1;
            float xc = cx ? xmx : xmn;
            int s0 = kx >> 3;
            int s1 = (kx + 1 < NB) ? ((kx + 1) >> 3) : s0;
#pragma unroll
            for (int cy = 0; cy < 2; ++cy) {
                float yc = cy ? ymx : ymn;
                float sg = ((cx ^ cy) ? -1.0f : 1.0f);
                unsigned long long lo =
                    (unsigned long long)__float_as_uint(xc) |
                    ((unsigned long long)__float_as_uint(yc) << 32);
                unsigned long long hi =
                    (unsigned long long)__float_as_uint(sg * wh) |
                    ((unsigned long long)__float_as_uint(sg * wv) << 32);
                {
                    int rank = atomicAdd(&lcnt[s0], 1);
                    int pos  = lbase[s0] + rank;
                    if (pos < CAP) {
                        size_t ip = ((size_t)s0 * CAP + pos) * 2;
                        __hip_atomic_store(&bkt64[ip], lo, __ATOMIC_RELAXED,
                                           __HIP_MEMORY_SCOPE_AGENT);
                        __hip_atomic_store(&bkt64[ip + 1], hi, __ATOMIC_RELAXED,
                                           __HIP_MEMORY_SCOPE_AGENT);
                    }
                }
                if (s1 != s0) {
                    int rank = atomicAdd(&lcnt[s1], 1);
                    int pos  = lbase[s1] + rank;
                    if (pos < CAP) {
                        size_t ip = ((size_t)s1 * CAP + pos) * 2;
                        __hip_atomic_store(&bkt64[ip], lo, __ATOMIC_RELAXED,
                                           __HIP_MEMORY_SCOPE_AGENT);
                        __hip_atomic_store(&bkt64[ip + 1], hi, __ATOMIC_RELAXED,
                                           __HIP_MEMORY_SCOPE_AGENT);
                    }
                }
            }
        }
    }
    __syncthreads();   /* drains this block's stores (vmcnt(0) before barrier) */

    /* ================= Barrier: all 256 blocks done emitting ============= */
    if (tid == 0) {
        atomicAdd(done, 1);                       /* device-scope RMW */
        while (__hip_atomic_load(done, __ATOMIC_ACQUIRE,
                                 __HIP_MEMORY_SCOPE_AGENT) < GBLK) {
            __builtin_amdgcn_s_sleep(4);
        }
    }
    __syncthreads();

    if (bid >= NSTRIPES) return;                  /* blocks 64..255 exit */

    /* ================= Phase S: stripe + lookback + epilogue ============= */
    int st = bid;
    int x0 = st * SW;
    int* accH = acc;
    int* accV = acc + SW * NB;
    float* fH = (float*)accH;
    float* fV = (float*)accV;

    for (int k = tid; k < 2 * SW * NB; k += 1024) acc[k] = 0;
    __syncthreads();

    int cnt = min(__hip_atomic_load(&gcur[st], __ATOMIC_RELAXED,
                                    __HIP_MEMORY_SCOPE_AGENT), CAP);
    for (int q = tid; q < cnt; q += 1024) {
        size_t ip = ((size_t)st * CAP + q) * 2;
        unsigned long long lo = __hip_atomic_load(&bkt64[ip], __ATOMIC_RELAXED,
                                                  __HIP_MEMORY_SCOPE_AGENT);
        unsigned long long hi = __hip_atomic_load(&bkt64[ip + 1], __ATOMIC_RELAXED,
                                                  __HIP_MEMORY_SCOPE_AGENT);
        float ix = __uint_as_float((unsigned)lo);
        float iy = __uint_as_float((unsigned)(lo >> 32));
        float iz = __uint_as_float((unsigned)hi);
        float iw = __uint_as_float((unsigned)(hi >> 32));
        int kx = min(NB - 1, (int)(ix * INV_H));
        int ky = min(NB - 1, (int)(iy * INV_H));
        float dx0 = (kx + 1) * BIN_H - ix;
        float dx1 = ix - kx * BIN_H;
        float dy0 = (ky + 1) * BIN_H - iy;
        float dy1 = iy - ky * BIN_H;
        bool y1ok = (ky + 1) < NB;
        int c = kx - x0;
#pragma unroll
        for (int cc = 0; cc < 2; ++cc) {
            int col = c + cc;
            if ((unsigned)col < SW) {
                float dx = cc ? dx1 : dx0;
                int b = col * NB + ky;
                atomicAdd(&accH[b], __float2int_rn(iz * dx * dy0 * FXS));
                atomicAdd(&accV[b], __float2int_rn(iw * dx * dy0 * FXS));
                if (y1ok) {
                    atomicAdd(&accH[b + 1], __float2int_rn(iz * dx * dy1 * FXS));
                    atomicAdd(&accV[b + 1], __float2int_rn(iw * dx * dy1 * FXS));
                }
            }
        }
    }
    __syncthreads();

    /* ---- y-scan (int->float fold on load): 8 rows x 512, 2 rows/pass ---- */
    int half = tid >> 9;
    int y    = tid & 511;
    int lane = tid & 63;
    int wv16 = tid >> 6;
    int wrow0 = half * 8;
#pragma unroll
    for (int rp = 0; rp < 4; ++rp) {
        int row = rp * 2 + half;
        float vH = (float)accH[row * NB + y] * INV_FXS;
        float vV = (float)accV[row * NB + y] * INV_FXS;
#pragma unroll
        for (int o = 1; o < 64; o <<= 1) {
            float a = __shfl_up(vH, o);
            float b = __shfl_up(vV, o);
            if (lane >= o) { vH += a; vV += b; }
        }
        if (lane == 63) { wsc[wv16] = vH; wsc[16 + wv16] = vV; }
        __syncthreads();
        float oh = 0.f, ov = 0.f;
        for (int j = wrow0; j < wv16; ++j) { oh += wsc[j]; ov += wsc[16 + j]; }
        fH[row * NB + y] = vH + oh;
        fV[row * NB + y] = vV + ov;
        __syncthreads();
    }

    /* ---- x-partial scan over the 8 rows + publish totals ---- */
    if (tid < NB) {
        float f = 0.f;
#pragma unroll
        for (int rr = 0; rr < SW; ++rr) {
            int i = rr * NB + tid;
            f += fH[i]; fH[i] = f;
        }
        __hip_atomic_store(&Th[st * NB + tid], f, __ATOMIC_RELAXED,
                           __HIP_MEMORY_SCOPE_AGENT);
    } else {
        int yy = tid - NB;
        float f = 0.f;
#pragma unroll
        for (int rr = 0; rr < SW; ++rr) {
            int i = rr * NB + yy;
            f += fV[i]; fV[i] = f;
        }
        __hip_atomic_store(&Tv[st * NB + yy], f, __ATOMIC_RELAXED,
                           __HIP_MEMORY_SCOPE_AGENT);
    }
    __syncthreads();
    if (tid == 0) {
        __threadfence();
        __hip_atomic_store(&flag[st], 1, __ATOMIC_RELEASE,
                           __HIP_MEMORY_SCOPE_AGENT);
    }

    /* ---- lookback ---- */
    if (tid < st) {
        while (__hip_atomic_load(&flag[tid], __ATOMIC_ACQUIRE,
                                 __HIP_MEMORY_SCOPE_AGENT) == 0) {
            __builtin_amdgcn_s_sleep(2);
        }
    }
    __syncthreads();
    {
        float sh = 0.f, sv = 0.f;
        for (int s2 = half; s2 < st; s2 += 2) {
            sh += __hip_atomic_load(&Th[s2 * NB + y], __ATOMIC_RELAXED,
                                    __HIP_MEMORY_SCOPE_AGENT);
            sv += __hip_atomic_load(&Tv[s2 * NB + y], __ATOMIC_RELAXED,
                                    __HIP_MEMORY_SCOPE_AGENT);
        }
        offHs[half][y] = sh;
        offVs[half][y] = sv;
    }
    __syncthreads();

    /* ---- fused epilogue straight from LDS ---- */
    {
        float offh = offHs[0][y] + offHs[1][y];
        float offv = offVs[0][y] + offVs[1][y];
#pragma unroll
        for (int r2 = 0; r2 < 4; ++r2) {
            int rr = half * 4 + r2;
            float h = fabsf(fH[rr * NB + y] + offh) * OUT_SCALE;
            float v = fabsf(fV[rr * NB + y] + offv) * OUT_SCALE;
            float m = fmaxf(h, v);
            out[(x0 + rr) * NB + y] = fminf(fmaxf(m * m, 0.5f), 2.0f);
        }
    }
}

// ---------------------------------------------------------------------------
// Fallback (tiny workspace): global-atomic scatter + scans
// ---------------------------------------------------------------------------
__global__ void scatter_kernel(const float* __restrict__ pin_pos,
                               const int*   __restrict__ flat_netpin,
                               const float* __restrict__ net_weights,
                               float* __restrict__ Uh,
                               float* __restrict__ Uv) {
    int n = blockIdx.x * blockDim.x + threadIdx.x;
    if (n >= NUM_NETS) return;
    float xmn = 1e30f, xmx = -1e30f, ymn = 1e30f, ymx = -1e30f;
#pragma unroll
    for (int p = 0; p < PINS_PER_NET; ++p) {
        int pi  = flat_netpin[n * PINS_PER_NET + p];
        float x = pin_pos[pi];
        float y = pin_pos[NUM_PINS + pi];
        xmn = fminf(xmn, x); xmx = fmaxf(xmx, x);
        ymn = fminf(ymn, y); ymx = fmaxf(ymx, y);
    }
    float w  = net_weights[n];
    float wh = w / (ymx - ymn), wv = w / (xmx - xmn);
    int kx1 = min(NB - 1, (int)(xmn * INV_H));
    int kx2 = min(NB - 1, (int)(xmx * INV_H));
    int ky1 = min(NB - 1, (int)(ymn * INV_H));
    int ky2 = min(NB - 1, (int)(ymx * INV_H));
    int   xi[4] = { kx1, kx1 + 1, kx2, kx2 + 1 };
    float xv[4] = { (kx1 + 1) * BIN_H - xmn,  xmn - kx1 * BIN_H,
                    xmx - (kx2 + 1) * BIN_H,  kx2 * BIN_H - xmx };
    int   yi[4] = { ky1, ky1 + 1, ky2, ky2 + 1 };
    float yv[4] = { (ky1 + 1) * BIN_H - ymn,  ymn - ky1 * BIN_H,
                    ymx - (ky2 + 1) * BIN_H,  ky2 * BIN_H - ymx };
#pragma unroll
    for (int a = 0; a < 4; ++a) {
        if (xi[a] >= NB) continue;
#pragma unroll
        for (int b2 = 0; b2 < 4; ++b2) {
            if (yi[b2] >= NB) continue;
            float prod = xv[a] * yv[b2];
            atomicAdd(&Uh[xi[a] * NB + yi[b2]], wh * prod);
            atomicAdd(&Uv[xi[a] * NB + yi[b2]], wv * prod);
        }
    }
}

__global__ void fb_rowscan_kernel(float* __restrict__ Uh, float* __restrict__ Uv) {
    __shared__ float sh[NB];
    __shared__ float sv[NB];
    int rr = blockIdx.x, t = threadIdx.x;
    sh[t] = Uh[rr * NB + t];
    sv[t] = Uv[rr * NB + t];
    __syncthreads();
#pragma unroll
    for (int off = 1; off < NB; off <<= 1) {
        float a = (t >= off) ? sh[t - off] : 0.0f;
        float b = (t >= off) ? sv[t - off] : 0.0f;
        __syncthreads();
        sh[t] += a; sv[t] += b;
        __syncthreads();
    }
    Uh[rr * NB + t] = sh[t];
    Uv[rr * NB + t] = sv[t];
}

__global__ void fb_colscan_kernel(const float* __restrict__ Uh,
                                  const float* __restrict__ Uv,
                                  float* __restrict__ out) {
    int t = blockIdx.x * blockDim.x + threadIdx.x;
    if (t >= NB) return;
    float sh = 0.f, sv = 0.f;
    for (int i = 0; i < NB; ++i) {
        sh += Uh[i * NB + t];
        sv += Uv[i * NB + t];
        float h = fabsf(sh) * OUT_SCALE;
        float v = fabsf(sv) * OUT_SCALE;
        float m = fmaxf(h, v);
        out[i * NB + t] = fminf(fmaxf(m * m, 0.5f), 2.0f);
    }
}

extern "C" void kernel_launch(void* const* d_in, const int* in_sizes, int n_in,
                              void* d_out, int out_size, void* d_ws, size_t ws_size,
                              hipStream_t stream) {
    const float* pin_pos     = (const float*)d_in[0];
    const int*   flat_netpin = (const int*)d_in[2];
    const float* net_weights = (const float*)d_in[3];
    float* out = (float*)d_out;
    float* ws  = (float*)d_ws;

    /* layout (floats): gcur[64] | flag[64] | done[1..pad 32] | (align)
                        bucket[64*CAP*4] | Th[64*512] | Tv[64*512] (~25.5 MB) */
    const size_t o_cur  = 0;
    const size_t o_flg  = 64;
    const size_t o_done = 128;
    const size_t o_bkt  = 160;                             /* 8B/16B aligned */
    const size_t o_Th   = o_bkt + (size_t)NSTRIPES * CAP * 4;
    const size_t o_Tv   = o_Th + (size_t)NSTRIPES * NB;
    const size_t need   = o_Tv + (size_t)NSTRIPES * NB;

    if (ws_size < need * sizeof(float)) {
        float* Uh = ws;
        float* Uv = ws + (size_t)NB * NB;
        hipMemsetAsync(ws, 0, 2 * (size_t)NB * NB * sizeof(float), stream);
        scatter_kernel<<<(NUM_NETS + 255) / 256, 256, 0, stream>>>(
            pin_pos, flat_netpin, net_weights, Uh, Uv);
        fb_rowscan_kernel<<<NB, NB, 0, stream>>>(Uh, Uv);
        fb_colscan_kernel<<<2, 256, 0, stream>>>(Uh, Uv, out);
        return;
    }

    int*                gcur  = (int*)(ws + o_cur);
    int*                flg   = (int*)(ws + o_flg);
    int*                done  = (int*)(ws + o_done);
    unsigned long long* bkt64 = (unsigned long long*)(ws + o_bkt);
    float*              Th    = ws + o_Th;
    float*              Tv    = ws + o_Tv;

    zero_kernel<<<1, 256, 0, stream>>>((int*)ws);  /* gcur+flag+done */

    fused_kernel<<<GBLK, 1024, 0, stream>>>(
        pin_pos, flat_netpin, net_weights, gcur, bkt64, Th, Tv, flg, done, out);
}

// Round 19
// 51.339 us; speedup vs baseline: 3.0695x; 3.0695x over previous
//
#include <hip/hip_runtime.h>

#define NUM_NETS     100000
#define PINS_PER_NET 5
#define NUM_PINS     (NUM_NETS * PINS_PER_NET)
#define NB           512
#define BIN_H        1.953125f          /* 1000/512, exact in fp32 */
#define INV_H        0.512f             /* 512/1000 */
#define OUT_SCALE    (1.0f / 195.3125f) /* 1/(BIN_SIZE_X * 100 tracks) */

#define SW           8                  /* stripe width (x bins) */
#define NSTRIPES     (NB / SW)          /* 64 */
#define NBK          (NSTRIPES * 2)     /* 128 buckets: stripe x y-half */
#define HH           256                /* bins per y-half */
#define CAP          12288              /* items per half-bucket (worst ~8.2K) */

#define FXS          2097152.0f         /* 2^21 fixed-point scale */
#define INV_FXS      (1.0f / 2097152.0f)

// ---------------------------------------------------------------------------
// K_0: zero cursors[128] + flagRT[64] + flagT[128] each replay.
// ---------------------------------------------------------------------------
__global__ void zero_kernel(int* __restrict__ p) {
    if (threadIdx.x < 320) p[threadIdx.x] = 0;
}

// ---------------------------------------------------------------------------
// K_A: bbox + emit 16B items into per-(stripe x y-half) buckets.
// Bucket id = (kx>>3)*2 + (ky>>8); straddles (kx and ky==255) duplicate.
// ---------------------------------------------------------------------------
__global__ __launch_bounds__(256) void bbox_emit_kernel(
        const float* __restrict__ pin_pos,
        const int*   __restrict__ flat_netpin,
        const float* __restrict__ net_weights,
        int* __restrict__ gcur,
        float4* __restrict__ bucket) {
    __shared__ int lcnt[NBK];
    __shared__ int lbase[NBK];
    int tid = threadIdx.x;
    if (tid < NBK) lcnt[tid] = 0;
    __syncthreads();

    int n = blockIdx.x * 256 + tid;
    bool valid = n < NUM_NETS;
    float xmn = 1e30f, xmx = -1e30f, ymn = 1e30f, ymx = -1e30f;
    float wh = 0.f, wv = 0.f;
    int kx1 = 0, kx2 = 0, ky1 = 0, ky2 = 0;
    if (valid) {
#pragma unroll
        for (int p = 0; p < PINS_PER_NET; ++p) {
            int pi  = flat_netpin[n * PINS_PER_NET + p];
            float x = pin_pos[pi];
            float y = pin_pos[NUM_PINS + pi];
            xmn = fminf(xmn, x); xmx = fmaxf(xmx, x);
            ymn = fminf(ymn, y); ymx = fmaxf(ymx, y);
        }
        float w = net_weights[n];
        wh = w / (ymx - ymn);
        wv = w / (xmx - xmn);
        kx1 = min(NB - 1, (int)(xmn * INV_H));
        kx2 = min(NB - 1, (int)(xmx * INV_H));
        ky1 = min(NB - 1, (int)(ymn * INV_H));
        ky2 = min(NB - 1, (int)(ymx * INV_H));
#pragma unroll
        for (int cx = 0; cx < 2; ++cx) {
            int kx = cx ? kx2 : kx1;
            int s0 = kx >> 3;
            int s1 = (kx + 1 < NB && ((kx + 1) >> 3) != s0) ? ((kx + 1) >> 3) : -1;
#pragma unroll
            for (int cy = 0; cy < 2; ++cy) {
                int ky = cy ? ky2 : ky1;
                int hh = ky >> 8;
                bool ystr = (ky == 255);
                atomicAdd(&lcnt[(s0 << 1) | hh], 1);
                if (ystr)     atomicAdd(&lcnt[(s0 << 1) | 1], 1);
                if (s1 >= 0) {
                    atomicAdd(&lcnt[(s1 << 1) | hh], 1);
                    if (ystr) atomicAdd(&lcnt[(s1 << 1) | 1], 1);
                }
            }
        }
    }
    __syncthreads();
    if (tid < NBK) {
        int c = lcnt[tid];
        lbase[tid] = c ? atomicAdd(&gcur[tid], c) : 0;
        lcnt[tid] = 0;
    }
    __syncthreads();
    if (valid) {
#pragma unroll
        for (int cx = 0; cx < 2; ++cx) {
            int   kx = cx ? kx2 : kx1;
            float xc = cx ? xmx : xmn;
            int s0 = kx >> 3;
            int s1 = (kx + 1 < NB && ((kx + 1) >> 3) != s0) ? ((kx + 1) >> 3) : -1;
#pragma unroll
            for (int cy = 0; cy < 2; ++cy) {
                int   ky = cy ? ky2 : ky1;
                float yc = cy ? ymx : ymn;
                int hh = ky >> 8;
                bool ystr = (ky == 255);
                float sg = ((cx ^ cy) ? -1.0f : 1.0f);
                float4 item = make_float4(xc, yc, sg * wh, sg * wv);
                int bs[4]; int nb = 0;
                bs[nb++] = (s0 << 1) | hh;
                if (ystr)     bs[nb++] = (s0 << 1) | 1;
                if (s1 >= 0) {
                    bs[nb++] = (s1 << 1) | hh;
                    if (ystr) bs[nb++] = (s1 << 1) | 1;
                }
                for (int j = 0; j < nb; ++j) {
                    int b = bs[j];
                    int rank = atomicAdd(&lcnt[b], 1);
                    int pos  = lbase[b] + rank;
                    if (pos < CAP) bucket[(size_t)b * CAP + pos] = item;
                }
            }
        }
    }
}

// ---------------------------------------------------------------------------
// K_B: half-stripe worker. Block = (stripe st, y-half h). Int-atomic
// accumulate 8x256 -> y-scan -> bottom publishes 8+8 rowtots (flag-spin) ->
// top adds them -> x-partial scan -> publish Th -> lookback -> epilogue.
// ---------------------------------------------------------------------------
__global__ __launch_bounds__(1024) void half_stripe_kernel(
        const float4* __restrict__ bucket,
        const int* __restrict__ gcur,
        float* __restrict__ rtH, float* __restrict__ rtV,
        int* __restrict__ flagRT,
        float* __restrict__ Th,  float* __restrict__ Tv,
        int* __restrict__ flagT,
        float* __restrict__ out) {
    __shared__ int   acc[2 * SW * HH];          /* 16 KB: H then V */
    __shared__ float wsc[4][4][2];
    __shared__ float rowtH[8], rowtV[8];
    __shared__ float btH[8],  btV[8];
    __shared__ float offH[4][HH];               /* 4 KB */
    __shared__ float offV[4][HH];               /* 4 KB */
    int bid = blockIdx.x;
    int st  = bid >> 1;
    int h   = bid & 1;
    int tid = threadIdx.x;
    int x0  = st * SW;
    int y0  = h * HH;
    int* accH = acc;
    int* accV = acc + SW * HH;
    float* fH = (float*)accH;
    float* fV = (float*)accV;

    for (int k = tid; k < 2 * SW * HH; k += 1024) acc[k] = 0;
    __syncthreads();

    /* ---- accumulate (int fixed-point, native LDS atomics) ---- */
    int cnt = min(gcur[bid], CAP);
    const float4* bk = bucket + (size_t)bid * CAP;
    for (int q = tid; q < cnt; q += 1024) {
        float4 it = bk[q];
        int kx = min(NB - 1, (int)(it.x * INV_H));
        int ky = min(NB - 1, (int)(it.y * INV_H));
        int gy = ky - y0;
        float dx0 = (kx + 1) * BIN_H - it.x;
        float dx1 = it.x - kx * BIN_H;
        float dy0 = (ky + 1) * BIN_H - it.y;
        float dy1 = it.y - ky * BIN_H;
        bool ok0 = (unsigned)gy < (unsigned)HH;
        bool ok1 = (ky + 1 < NB) && ((unsigned)(gy + 1) < (unsigned)HH);
        int c = kx - x0;
#pragma unroll
        for (int cc = 0; cc < 2; ++cc) {
            int col = c + cc;
            if ((unsigned)col < SW) {
                float dx = cc ? dx1 : dx0;
                if (ok0) {
                    int b = col * HH + gy;
                    atomicAdd(&accH[b], __float2int_rn(it.z * dx * dy0 * FXS));
                    atomicAdd(&accV[b], __float2int_rn(it.w * dx * dy0 * FXS));
                }
                if (ok1) {
                    int b = col * HH + gy + 1;
                    atomicAdd(&accH[b], __float2int_rn(it.z * dx * dy1 * FXS));
                    atomicAdd(&accV[b], __float2int_rn(it.w * dx * dy1 * FXS));
                }
            }
        }
    }
    __syncthreads();

    /* ---- y-scan (int->float on load): 2 passes x 4 rows x 256 ---- */
    int lane = tid & 63;
    int wwi  = (tid >> 6) & 3;      /* wave within row */
    int rg   = tid >> 8;            /* row group 0..3 */
    int y    = tid & 255;
#pragma unroll
    for (int pass = 0; pass < 2; ++pass) {
        int row = pass * 4 + rg;
        float vH = (float)accH[row * HH + y] * INV_FXS;
        float vV = (float)accV[row * HH + y] * INV_FXS;
#pragma unroll
        for (int o = 1; o < 64; o <<= 1) {
            float a = __shfl_up(vH, o);
            float b = __shfl_up(vV, o);
            if (lane >= o) { vH += a; vV += b; }
        }
        if (lane == 63) { wsc[rg][wwi][0] = vH; wsc[rg][wwi][1] = vV; }
        __syncthreads();
        float oh = 0.f, ov = 0.f;
        for (int j = 0; j < wwi; ++j) { oh += wsc[rg][j][0]; ov += wsc[rg][j][1]; }
        vH += oh; vV += ov;
        fH[row * HH + y] = vH;
        fV[row * HH + y] = vV;
        if (lane == 63 && wwi == 3) { rowtH[row] = vH; rowtV[row] = vV; }
        __syncthreads();
    }

    /* ---- rowtot handoff: bottom publishes, top consumes ---- */
    if (h == 0) {
        if (tid < 8) {
            __hip_atomic_store(&rtH[st * 8 + tid], rowtH[tid], __ATOMIC_RELAXED,
                               __HIP_MEMORY_SCOPE_AGENT);
            __hip_atomic_store(&rtV[st * 8 + tid], rowtV[tid], __ATOMIC_RELAXED,
                               __HIP_MEMORY_SCOPE_AGENT);
        }
        if (tid < 8) { btH[tid] = 0.f; btV[tid] = 0.f; }
        __syncthreads();
        if (tid == 0) {
            __threadfence();
            __hip_atomic_store(&flagRT[st], 1, __ATOMIC_RELEASE,
                               __HIP_MEMORY_SCOPE_AGENT);
        }
    } else {
        if (tid == 0) {
            while (__hip_atomic_load(&flagRT[st], __ATOMIC_ACQUIRE,
                                     __HIP_MEMORY_SCOPE_AGENT) == 0) {
                __builtin_amdgcn_s_sleep(2);
            }
        }
        __syncthreads();
        if (tid < 8) {
            btH[tid] = __hip_atomic_load(&rtH[st * 8 + tid], __ATOMIC_RELAXED,
                                         __HIP_MEMORY_SCOPE_AGENT);
            btV[tid] = __hip_atomic_load(&rtV[st * 8 + tid], __ATOMIC_RELAXED,
                                         __HIP_MEMORY_SCOPE_AGENT);
        }
        __syncthreads();
    }

    /* ---- x-partial scan over 8 rows (+bottom offset) + publish Th ---- */
    if (tid < HH) {
        float f = 0.f;
#pragma unroll
        for (int rr = 0; rr < SW; ++rr) {
            int i = rr * HH + tid;
            f += fH[i] + btH[rr];
            fH[i] = f;
        }
        __hip_atomic_store(&Th[bid * HH + tid], f, __ATOMIC_RELAXED,
                           __HIP_MEMORY_SCOPE_AGENT);
    } else if (tid < 2 * HH) {
        int yy = tid - HH;
        float f = 0.f;
#pragma unroll
        for (int rr = 0; rr < SW; ++rr) {
            int i = rr * HH + yy;
            f += fV[i] + btV[rr];
            fV[i] = f;
        }
        __hip_atomic_store(&Tv[bid * HH + yy], f, __ATOMIC_RELAXED,
                           __HIP_MEMORY_SCOPE_AGENT);
    }
    __syncthreads();
    if (tid == 0) {
        __threadfence();
        __hip_atomic_store(&flagT[bid], 1, __ATOMIC_RELEASE,
                           __HIP_MEMORY_SCOPE_AGENT);
    }

    /* ---- lookback over same-half lower stripes ---- */
    if (tid < st) {
        while (__hip_atomic_load(&flagT[tid * 2 + h], __ATOMIC_ACQUIRE,
                                 __HIP_MEMORY_SCOPE_AGENT) == 0) {
            __builtin_amdgcn_s_sleep(2);
        }
    }
    __syncthreads();
    {
        float sh = 0.f, sv = 0.f;
        for (int s2 = rg; s2 < st; s2 += 4) {
            sh += __hip_atomic_load(&Th[(s2 * 2 + h) * HH + y], __ATOMIC_RELAXED,
                                    __HIP_MEMORY_SCOPE_AGENT);
            sv += __hip_atomic_load(&Tv[(s2 * 2 + h) * HH + y], __ATOMIC_RELAXED,
                                    __HIP_MEMORY_SCOPE_AGENT);
        }
        offH[rg][y] = sh;
        offV[rg][y] = sv;
    }
    __syncthreads();

    /* ---- fused epilogue straight from LDS ---- */
    {
        float oh = offH[0][y] + offH[1][y] + offH[2][y] + offH[3][y];
        float ov = offV[0][y] + offV[1][y] + offV[2][y] + offV[3][y];
#pragma unroll
        for (int r2 = 0; r2 < 2; ++r2) {
            int rr = rg * 2 + r2;
            float hv = fabsf(fH[rr * HH + y] + oh) * OUT_SCALE;
            float vv = fabsf(fV[rr * HH + y] + ov) * OUT_SCALE;
            float m = fmaxf(hv, vv);
            out[(x0 + rr) * NB + y0 + y] = fminf(fmaxf(m * m, 0.5f), 2.0f);
        }
    }
}

// ---------------------------------------------------------------------------
// Fallback (tiny workspace): global-atomic scatter + scans
// ---------------------------------------------------------------------------
__global__ void scatter_kernel(const float* __restrict__ pin_pos,
                               const int*   __restrict__ flat_netpin,
                               const float* __restrict__ net_weights,
                               float* __restrict__ Uh,
                               float* __restrict__ Uv) {
    int n = blockIdx.x * blockDim.x + threadIdx.x;
    if (n >= NUM_NETS) return;
    float xmn = 1e30f, xmx = -1e30f, ymn = 1e30f, ymx = -1e30f;
#pragma unroll
    for (int p = 0; p < PINS_PER_NET; ++p) {
        int pi  = flat_netpin[n * PINS_PER_NET + p];
        float x = pin_pos[pi];
        float y = pin_pos[NUM_PINS + pi];
        xmn = fminf(xmn, x); xmx = fmaxf(xmx, x);
        ymn = fminf(ymn, y); ymx = fmaxf(ymx, y);
    }
    float w  = net_weights[n];
    float wh = w / (ymx - ymn), wv = w / (xmx - xmn);
    int kx1 = min(NB - 1, (int)(xmn * INV_H));
    int kx2 = min(NB - 1, (int)(xmx * INV_H));
    int ky1 = min(NB - 1, (int)(ymn * INV_H));
    int ky2 = min(NB - 1, (int)(ymx * INV_H));
    int   xi[4] = { kx1, kx1 + 1, kx2, kx2 + 1 };
    float xv[4] = { (kx1 + 1) * BIN_H - xmn,  xmn - kx1 * BIN_H,
                    xmx - (kx2 + 1) * BIN_H,  kx2 * BIN_H - xmx };
    int   yi[4] = { ky1, ky1 + 1, ky2, ky2 + 1 };
    float yv[4] = { (ky1 + 1) * BIN_H - ymn,  ymn - ky1 * BIN_H,
                    ymx - (ky2 + 1) * BIN_H,  ky2 * BIN_H - ymx };
#pragma unroll
    for (int a = 0; a < 4; ++a) {
        if (xi[a] >= NB) continue;
#pragma unroll
        for (int b2 = 0; b2 < 4; ++b2) {
            if (yi[b2] >= NB) continue;
            float prod = xv[a] * yv[b2];
            atomicAdd(&Uh[xi[a] * NB + yi[b2]], wh * prod);
            atomicAdd(&Uv[xi[a] * NB + yi[b2]], wv * prod);
        }
    }
}

__global__ void fb_rowscan_kernel(float* __restrict__ Uh, float* __restrict__ Uv) {
    __shared__ float sh[NB];
    __shared__ float sv[NB];
    int rr = blockIdx.x, t = threadIdx.x;
    sh[t] = Uh[rr * NB + t];
    sv[t] = Uv[rr * NB + t];
    __syncthreads();
#pragma unroll
    for (int off = 1; off < NB; off <<= 1) {
        float a = (t >= off) ? sh[t - off] : 0.0f;
        float b = (t >= off) ? sv[t - off] : 0.0f;
        __syncthreads();
        sh[t] += a; sv[t] += b;
        __syncthreads();
    }
    Uh[rr * NB + t] = sh[t];
    Uv[rr * NB + t] = sv[t];
}

__global__ void fb_colscan_kernel(const float* __restrict__ Uh,
                                  const float* __restrict__ Uv,
                                  float* __restrict__ out) {
    int t = blockIdx.x * blockDim.x + threadIdx.x;
    if (t >= NB) return;
    float sh = 0.f, sv = 0.f;
    for (int i = 0; i < NB; ++i) {
        sh += Uh[i * NB + t];
        sv += Uv[i * NB + t];
        float h = fabsf(sh) * OUT_SCALE;
        float v = fabsf(sv) * OUT_SCALE;
        float m = fmaxf(h, v);
        out[i * NB + t] = fminf(fmaxf(m * m, 0.5f), 2.0f);
    }
}

extern "C" void kernel_launch(void* const* d_in, const int* in_sizes, int n_in,
                              void* d_out, int out_size, void* d_ws, size_t ws_size,
                              hipStream_t stream) {
    const float* pin_pos     = (const float*)d_in[0];
    const int*   flat_netpin = (const int*)d_in[2];
    const float* net_weights = (const float*)d_in[3];
    float* out = (float*)d_out;
    float* ws  = (float*)d_ws;

    /* layout (floats): gcur[128] flagRT[64] flagT[128] rtH[512] rtV[512]
       bucket[128*CAP*4] Th[128*256] Tv[128*256]                (~25.4 MB) */
    const size_t o_cur = 0;
    const size_t o_fRT = 128;
    const size_t o_fT  = 192;
    const size_t o_rtH = 320;
    const size_t o_rtV = o_rtH + 512;
    const size_t o_bkt = o_rtV + 512;              /* 1344: 16B aligned */
    const size_t o_Th  = o_bkt + (size_t)NBK * CAP * 4;
    const size_t o_Tv  = o_Th + (size_t)NBK * HH;
    const size_t need  = o_Tv + (size_t)NBK * HH;

    if (ws_size < need * sizeof(float)) {
        float* Uh = ws;
        float* Uv = ws + (size_t)NB * NB;
        hipMemsetAsync(ws, 0, 2 * (size_t)NB * NB * sizeof(float), stream);
        scatter_kernel<<<(NUM_NETS + 255) / 256, 256, 0, stream>>>(
            pin_pos, flat_netpin, net_weights, Uh, Uv);
        fb_rowscan_kernel<<<NB, NB, 0, stream>>>(Uh, Uv);
        fb_colscan_kernel<<<2, 256, 0, stream>>>(Uh, Uv, out);
        return;
    }

    int*    gcur   = (int*)(ws + o_cur);
    int*    fRT    = (int*)(ws + o_fRT);
    int*    fT     = (int*)(ws + o_fT);
    float*  rtH    = ws + o_rtH;
    float*  rtV    = ws + o_rtV;
    float4* bucket = (float4*)(ws + o_bkt);
    float*  Th     = ws + o_Th;
    float*  Tv     = ws + o_Tv;

    zero_kernel<<<1, 512, 0, stream>>>((int*)ws);  /* gcur + flagRT + flagT */

    bbox_emit_kernel<<<(NUM_NETS + 255) / 256, 256, 0, stream>>>(
        pin_pos, flat_netpin, net_weights, gcur, bucket);

    half_stripe_kernel<<<NBK, 1024, 0, stream>>>(
        bucket, gcur, rtH, rtV, fRT, Th, Tv, fT, out);
}